// Round 1
// baseline (1283.876 us; speedup 1.0000x reference)
//
#include <hip/hip_runtime.h>
#include <math.h>

#define LSEQ 2304
#define DM 128
#define DI 256
#define DS 16
#define RK 8
#define NCH 36
#define CLEN 64
#define EPSF 1e-5f

// ---------------------------------------------------------------------------
// K1: xz[l][j] = sum_c seq[l][c] * W_in[c][j]   (M=2304, K=128, N=512)
// block = 256 threads, 16 rows per block; each thread: col j and j+256.
template<bool FIRST>
__global__ void k_gemm_in(const float* __restrict__ seq, const float* __restrict__ x0,
                          const float* __restrict__ W, float* __restrict__ xz) {
    __shared__ float As[16][DM];
    const int l0 = blockIdx.x * 16;
    const int tid = threadIdx.x;
    for (int i = tid; i < 16 * DM; i += 256) {
        int r = i >> 7, c = i & 127;
        As[r][c] = FIRST ? x0[c * LSEQ + (l0 + r)] : seq[(l0 + r) * DM + c];
    }
    __syncthreads();
    float acc0[16], acc1[16];
#pragma unroll
    for (int r = 0; r < 16; ++r) { acc0[r] = 0.f; acc1[r] = 0.f; }
    const int j = tid;
    for (int k = 0; k < DM; ++k) {
        float b0 = W[k * 512 + j];
        float b1 = W[k * 512 + j + 256];
#pragma unroll
        for (int r = 0; r < 16; ++r) {
            float a = As[r][k];
            acc0[r] += a * b0;
            acc1[r] += a * b1;
        }
    }
#pragma unroll
    for (int r = 0; r < 16; ++r) {
        xz[(l0 + r) * 512 + j] = acc0[r];
        xz[(l0 + r) * 512 + j + 256] = acc1[r];
    }
}

__device__ __forceinline__ float silu_f(float s) {
    return s / (1.f + expf(-s));
}

// ---------------------------------------------------------------------------
// K2: causal conv(4) + silu -> xc; xc @ W_xproj -> (dt_r, Bs, Cs);
//     softplus(dt_r @ W_dt + b_dt) -> dt.   8 rows per block, 256 threads.
__global__ void k_conv_proj(const float* __restrict__ xz,
                            const float* __restrict__ cw, const float* __restrict__ cb,
                            const float* __restrict__ Wx,
                            const float* __restrict__ Wdt, const float* __restrict__ bdt,
                            float* __restrict__ xc, float* __restrict__ dbl,
                            float* __restrict__ dt) {
    __shared__ float xcs[8][DI];
    __shared__ float dtr[8][RK];
    const int l0 = blockIdx.x * 8;
    const int tid = threadIdx.x;

    // --- conv + silu : thread = channel d, 8 rows ---
    {
        const int d = tid;
        const float w0 = cw[d * 4 + 0], w1 = cw[d * 4 + 1];
        const float w2 = cw[d * 4 + 2], w3 = cw[d * 4 + 3];
        const float bias = cb[d];
#pragma unroll
        for (int r = 0; r < 8; ++r) {
            const int l = l0 + r;
            float s = bias;
            s += (l >= 3 ? xz[(l - 3) * 512 + d] : 0.f) * w0;
            s += (l >= 2 ? xz[(l - 2) * 512 + d] : 0.f) * w1;
            s += (l >= 1 ? xz[(l - 1) * 512 + d] : 0.f) * w2;
            s += xz[l * 512 + d] * w3;
            float v = silu_f(s);
            xcs[r][d] = v;
            xc[l * DI + d] = v;
        }
    }
    __syncthreads();

    // --- xproj: 8 rows x 40 outputs, K=256 ---
    for (int idx = tid; idx < 8 * 40; idx += 256) {
        const int r = idx / 40, j = idx % 40;
        float acc = 0.f;
        for (int k = 0; k < DI; ++k) acc += xcs[r][k] * Wx[k * 40 + j];
        if (j < RK) dtr[r][j] = acc;
        else dbl[(l0 + r) * 32 + (j - RK)] = acc;
    }
    __syncthreads();

    // --- dt = softplus(dt_r @ Wdt + bdt): 8 rows x 256 ---
    for (int idx = tid; idx < 8 * DI; idx += 256) {
        const int r = idx >> 8, dd = idx & 255;
        float acc = bdt[dd];
#pragma unroll
        for (int q = 0; q < RK; ++q) acc += dtr[r][q] * Wdt[q * DI + dd];
        float sp = (acc > 20.f) ? acc : log1pf(expf(acc));
        dt[(l0 + r) * DI + dd] = sp;
    }
}

// ---------------------------------------------------------------------------
// K3: per-chunk scan factors. grid (NCH, DI/16); block 256 = 16d x 16s.
__global__ void k_scan1(const float* __restrict__ dt, const float* __restrict__ xc,
                        const float* __restrict__ dbl, const float* __restrict__ Alog,
                        float* __restrict__ P, float* __restrict__ S) {
    const int c = blockIdx.x;
    const int tid = threadIdx.x;
    const int dl = tid >> 4, s = tid & 15;
    const int d = blockIdx.y * 16 + dl;
    const float A = -expf(Alog[d * DS + s]);
    float p = 1.f, h = 0.f;
    const int lbase = c * CLEN;
    for (int t = 0; t < CLEN; ++t) {
        const int l = lbase + t;
        const float dtv = dt[l * DI + d];
        const float xcv = xc[l * DI + d];
        const float Bv  = dbl[l * 32 + s];
        const float a = expf(dtv * A);
        p *= a;
        h = a * h + dtv * xcv * Bv;
    }
    const int idx = c * (DI * DS) + d * DS + s;
    P[idx] = p;
    S[idx] = h;
}

// ---------------------------------------------------------------------------
// K4: carry combine (redundant per chunk) + re-scan + y.
__global__ void k_scan2(const float* __restrict__ dt, const float* __restrict__ xc,
                        const float* __restrict__ dbl, const float* __restrict__ Alog,
                        const float* __restrict__ P, const float* __restrict__ S,
                        const float* __restrict__ Dp, const float* __restrict__ xz,
                        float* __restrict__ y) {
    const int c = blockIdx.x;
    const int tid = threadIdx.x;
    const int dl = tid >> 4, s = tid & 15;
    const int d = blockIdx.y * 16 + dl;
    const float A = -expf(Alog[d * DS + s]);
    float h = 0.f;
    for (int cc = 0; cc < c; ++cc) {
        const int idx = cc * (DI * DS) + d * DS + s;
        h = P[idx] * h + S[idx];
    }
    const float dskip = Dp[d];
    const int lbase = c * CLEN;
    for (int t = 0; t < CLEN; ++t) {
        const int l = lbase + t;
        const float dtv = dt[l * DI + d];
        const float xcv = xc[l * DI + d];
        const float Bv  = dbl[l * 32 + s];
        const float Cv  = dbl[l * 32 + 16 + s];
        const float a = expf(dtv * A);
        h = a * h + dtv * xcv * Bv;
        float contrib = h * Cv;
        contrib += __shfl_xor(contrib, 1);
        contrib += __shfl_xor(contrib, 2);
        contrib += __shfl_xor(contrib, 4);
        contrib += __shfl_xor(contrib, 8);
        if (s == 0) {
            const float zv = xz[l * 512 + 256 + d];
            float yv = contrib + dskip * xcv;
            yv = yv * silu_f(zv);
            y[l * DI + d] = yv;
        }
    }
}

// ---------------------------------------------------------------------------
// K5: out = rmsnorm(y @ W_out) ; last layer writes transposed into d_out.
template<bool LAST>
__global__ void k_out(const float* __restrict__ y, const float* __restrict__ Wo,
                      const float* __restrict__ rmsw, float* __restrict__ seq,
                      float* __restrict__ out) {
    __shared__ float Ys[16][DI];
    __shared__ float Os[16][DM];
    __shared__ float red[16][8];
    __shared__ float scale[16];
    const int l0 = blockIdx.x * 16;
    const int tid = threadIdx.x;  // 128
    for (int i = tid; i < 16 * DI; i += 128) {
        int r = i >> 8, k = i & 255;
        Ys[r][k] = y[(l0 + r) * DI + k];
    }
    __syncthreads();
    float acc[16];
#pragma unroll
    for (int r = 0; r < 16; ++r) acc[r] = 0.f;
    const int cc = tid;
    for (int k = 0; k < DI; ++k) {
        float b = Wo[k * DM + cc];
#pragma unroll
        for (int r = 0; r < 16; ++r) acc[r] += Ys[r][k] * b;
    }
#pragma unroll
    for (int r = 0; r < 16; ++r) Os[r][cc] = acc[r];
    __syncthreads();
    {
        const int r = tid >> 3, part = tid & 7;
        float ss = 0.f;
#pragma unroll
        for (int i = 0; i < 16; ++i) {
            float v = Os[r][part * 16 + i];
            ss += v * v;
        }
        red[r][part] = ss;
    }
    __syncthreads();
    if (tid < 16) {
        float ss = 0.f;
#pragma unroll
        for (int p = 0; p < 8; ++p) ss += red[tid][p];
        scale[tid] = rsqrtf(ss * (1.f / DM) + EPSF);
    }
    __syncthreads();
    const float rw = rmsw[cc];
#pragma unroll
    for (int r = 0; r < 16; ++r) {
        float v = Os[r][cc] * scale[r] * rw;
        if (LAST) out[cc * LSEQ + (l0 + r)] = v;
        else      seq[(l0 + r) * DM + cc] = v;
    }
}

// ---------------------------------------------------------------------------
extern "C" void kernel_launch(void* const* d_in, const int* in_sizes, int n_in,
                              void* d_out, int out_size, void* d_ws, size_t ws_size,
                              hipStream_t stream) {
    const float* x    = (const float*)d_in[0];
    const float* W_in = (const float*)d_in[1];
    const float* cw   = (const float*)d_in[2];
    const float* cb   = (const float*)d_in[3];
    const float* Wx   = (const float*)d_in[4];
    const float* Wdt  = (const float*)d_in[5];
    const float* bdt  = (const float*)d_in[6];
    const float* Alog = (const float*)d_in[7];
    const float* Dp   = (const float*)d_in[8];
    const float* Wo   = (const float*)d_in[9];
    const float* rmsw = (const float*)d_in[10];
    float* out = (float*)d_out;

    float* ws  = (float*)d_ws;
    float* seq = ws;  ws += LSEQ * DM;
    float* xz  = ws;  ws += LSEQ * 512;
    float* xcb = ws;  ws += LSEQ * DI;
    float* dbl = ws;  ws += LSEQ * 32;
    float* dtb = ws;  ws += LSEQ * DI;
    float* Pb  = ws;  ws += NCH * DI * DS;
    float* Sb  = ws;  ws += NCH * DI * DS;
    float* yb  = ws;  ws += LSEQ * DI;

    for (int layer = 0; layer < 8; ++layer) {
        const float* Wi_l   = W_in + (size_t)layer * DM * 512;
        const float* cw_l   = cw   + (size_t)layer * DI * 4;
        const float* cb_l   = cb   + (size_t)layer * DI;
        const float* Wx_l   = Wx   + (size_t)layer * DI * 40;
        const float* Wdt_l  = Wdt  + (size_t)layer * RK * DI;
        const float* bdt_l  = bdt  + (size_t)layer * DI;
        const float* Alog_l = Alog + (size_t)layer * DI * DS;
        const float* Dp_l   = Dp   + (size_t)layer * DI;
        const float* Wo_l   = Wo   + (size_t)layer * DI * DM;
        const float* rmsw_l = rmsw + (size_t)layer * DM;

        if (layer == 0)
            k_gemm_in<true><<<LSEQ / 16, 256, 0, stream>>>(seq, x, Wi_l, xz);
        else
            k_gemm_in<false><<<LSEQ / 16, 256, 0, stream>>>(seq, x, Wi_l, xz);

        k_conv_proj<<<LSEQ / 8, 256, 0, stream>>>(xz, cw_l, cb_l, Wx_l, Wdt_l, bdt_l,
                                                  xcb, dbl, dtb);

        k_scan1<<<dim3(NCH, DI / 16), 256, 0, stream>>>(dtb, xcb, dbl, Alog_l, Pb, Sb);
        k_scan2<<<dim3(NCH, DI / 16), 256, 0, stream>>>(dtb, xcb, dbl, Alog_l, Pb, Sb,
                                                        Dp_l, xz, yb);

        if (layer == 7)
            k_out<true><<<LSEQ / 16, 128, 0, stream>>>(yb, Wo_l, rmsw_l, seq, out);
        else
            k_out<false><<<LSEQ / 16, 128, 0, stream>>>(yb, Wo_l, rmsw_l, seq, out);
    }
}

// Round 2
// 1092.224 us; speedup vs baseline: 1.1755x; 1.1755x over previous
//
#include <hip/hip_runtime.h>
#include <math.h>

#define LSEQ 2304
#define DM 128
#define DI 256
#define DS 16
#define RK 8
#define NCH 144
#define CLEN 16
#define EPSF 1e-5f

__device__ __forceinline__ float silu_f(float s) { return s / (1.f + expf(-s)); }
__device__ __forceinline__ float softplus_f(float x) { return (x > 20.f) ? x : log1pf(expf(x)); }

// ---------------------------------------------------------------------------
// K1: [xbuf|zbuf] = seq @ W_in   (M=2304, K=128, N=512)
// grid (144, 4): 16 rows x 128 cols per block; 256 thr = 128 cols x 2 rowgroups.
template<bool FIRST>
__global__ void k_gemm_in(const float* __restrict__ seq, const float* __restrict__ x0,
                          const float* __restrict__ W, float* __restrict__ xbuf,
                          float* __restrict__ zbuf) {
    __shared__ float As[16 * 129];
    const int l0 = blockIdx.x * 16;
    const int cb = blockIdx.y;  // 0..3
    const int tid = threadIdx.x;
    if (FIRST) {
        for (int i = tid; i < 16 * DM; i += 256) {
            int r = i & 15, c = i >> 4;
            As[r * 129 + c] = x0[c * LSEQ + l0 + r];
        }
    } else {
        for (int i = tid; i < 16 * DM; i += 256) {
            int c = i & 127, r = i >> 7;
            As[r * 129 + c] = seq[(l0 + r) * DM + c];
        }
    }
    __syncthreads();
    const int j = tid & 127;
    const int rg = tid >> 7;  // 0..1
    const int jg = cb * 128 + j;
    float acc[8];
#pragma unroll
    for (int rr = 0; rr < 8; ++rr) acc[rr] = 0.f;
    for (int k = 0; k < DM; ++k) {
        const float b = W[k * 512 + jg];
#pragma unroll
        for (int rr = 0; rr < 8; ++rr) acc[rr] += As[(rg * 8 + rr) * 129 + k] * b;
    }
    if (cb < 2) {
#pragma unroll
        for (int rr = 0; rr < 8; ++rr)
            xbuf[(l0 + rg * 8 + rr) * DI + jg] = acc[rr];
    } else {
#pragma unroll
        for (int rr = 0; rr < 8; ++rr)
            zbuf[(l0 + rg * 8 + rr) * DI + (jg - 256)] = acc[rr];
    }
}

// ---------------------------------------------------------------------------
// K2 (k_mid): conv4+silu -> xc ; xc @ W_xproj -> (dt_r, B, C) ; dt=softplus(...);
//             chunk-local scan -> P, S.   One block per 16-row chunk, 256 thr.
__global__ void k_mid(const float* __restrict__ xbuf,
                      const float* __restrict__ cw, const float* __restrict__ cbias,
                      const float* __restrict__ Wx,
                      const float* __restrict__ Wdt, const float* __restrict__ bdt,
                      const float* __restrict__ Alog,
                      float* __restrict__ xc_g, float* __restrict__ dbl_g,
                      float* __restrict__ dtr_g,
                      float* __restrict__ P, float* __restrict__ S) {
    __shared__ float WxT[40 * 260];   // [j][k] transposed, padded
    __shared__ float xcs[16 * 256];   // [r][d]
    __shared__ float dbls[16 * 32];   // [r][j-8]
    __shared__ float dtrs[16 * 8];    // [r][q]
    const int c = blockIdx.x;
    const int l0 = c * CLEN;
    const int tid = threadIdx.x;

    // stage Wx transposed
    for (int i = tid; i < DI * 40; i += 256) {
        int k = i / 40, j = i - k * 40;
        WxT[j * 260 + k] = Wx[i];
    }

    // conv + silu (thread = channel d)
    const int d = tid;
    float xv[19];
#pragma unroll
    for (int t = 0; t < 19; ++t) {
        int l = l0 + t - 3;
        xv[t] = (l >= 0) ? xbuf[l * DI + d] : 0.f;
    }
    const float w0 = cw[d * 4 + 0], w1 = cw[d * 4 + 1];
    const float w2 = cw[d * 4 + 2], w3 = cw[d * 4 + 3];
    const float bias = cbias[d];
    float xcv[16];
#pragma unroll
    for (int r = 0; r < 16; ++r) {
        float sacc = bias + w0 * xv[r] + w1 * xv[r + 1] + w2 * xv[r + 2] + w3 * xv[r + 3];
        float v = silu_f(sacc);
        xcv[r] = v;
        xcs[r * 256 + d] = v;
        xc_g[(l0 + r) * DI + d] = v;
    }
    __syncthreads();

    // xproj: 640 outputs (16 r x 40 j), K=256
    for (int idx = tid; idx < 16 * 40; idx += 256) {
        const int r = idx / 40, j = idx - r * 40;
        const float* xr = &xcs[r * 256];
        const float* wj = &WxT[j * 260];
        float acc = 0.f;
        for (int k = 0; k < 256; k += 4) {
            float4 a = *(const float4*)(xr + k);
            float4 b = *(const float4*)(wj + k);
            acc += a.x * b.x; acc += a.y * b.y; acc += a.z * b.z; acc += a.w * b.w;
        }
        if (j < RK) {
            dtrs[r * 8 + j] = acc;
            dtr_g[(l0 + r) * 8 + j] = acc;
        } else {
            dbls[r * 32 + (j - 8)] = acc;
            dbl_g[(l0 + r) * 32 + (j - 8)] = acc;
        }
    }
    __syncthreads();

    // dt = softplus(dt_r @ Wdt + bdt)  (thread = d, all 16 rows in regs)
    float wdt[8];
#pragma unroll
    for (int q = 0; q < 8; ++q) wdt[q] = Wdt[q * DI + d];
    const float bdv = bdt[d];
    float dtv[16];
#pragma unroll
    for (int r = 0; r < 16; ++r) {
        float acc = bdv;
#pragma unroll
        for (int q = 0; q < 8; ++q) acc += dtrs[r * 8 + q] * wdt[q];
        dtv[r] = softplus_f(acc);
    }

    // chunk-local scan: thread d holds 16 states
    float A[16], pr[16], hr[16];
#pragma unroll
    for (int s = 0; s < 16; ++s) {
        A[s] = -expf(Alog[d * DS + s]);
        pr[s] = 1.f;
        hr[s] = 0.f;
    }
    for (int t = 0; t < CLEN; ++t) {
        const float commonv = dtv[t] * xcv[t];
        const float dtt = dtv[t];
        const float* Brow = &dbls[t * 32];
#pragma unroll
        for (int s = 0; s < 16; ++s) {
            float a = expf(dtt * A[s]);
            pr[s] *= a;
            hr[s] = a * hr[s] + commonv * Brow[s];
        }
    }
    const int base = c * (DI * DS) + d * DS;
#pragma unroll
    for (int s = 0; s < 16; ++s) {
        P[base + s] = pr[s];
        S[base + s] = hr[s];
    }
}

// ---------------------------------------------------------------------------
// K3: chunk carries, in place: S[c] <- carry INTO chunk c. grid 16 x 256.
__global__ void k_carry(const float* __restrict__ P, float* __restrict__ S) {
    const int i = blockIdx.x * 256 + threadIdx.x;
    float h = 0.f;
    for (int c = 0; c < NCH; ++c) {
        const int idx = c * (DI * DS) + i;
        const float p = P[idx];
        const float s = S[idx];
        S[idx] = h;
        h = p * h + s;
    }
}

// ---------------------------------------------------------------------------
// K4: re-scan with carry + C-reduction via LDS transpose + gate -> y.
// grid (144, 16); block 256 = 16 d x 16 s.
__global__ void k_scan2(const float* __restrict__ xc_g, const float* __restrict__ dbl_g,
                        const float* __restrict__ dtr_g,
                        const float* __restrict__ Wdt, const float* __restrict__ bdt,
                        const float* __restrict__ Alog, const float* __restrict__ H,
                        const float* __restrict__ Dp, const float* __restrict__ zbuf,
                        float* __restrict__ y) {
    __shared__ float prod[16 * 16 * 17];  // [dl][s][t pad 17]
    const int c = blockIdx.x, by = blockIdx.y;
    const int tid = threadIdx.x;
    const int dl = tid >> 4, s = tid & 15;
    const int d = by * 16 + dl;
    const float A = -expf(Alog[d * DS + s]);
    float wdt[8];
#pragma unroll
    for (int q = 0; q < 8; ++q) wdt[q] = Wdt[q * DI + d];
    const float bdv = bdt[d];
    float h = H[c * (DI * DS) + by * 256 + tid];
    const int l0 = c * CLEN;
    for (int t = 0; t < CLEN; ++t) {
        const int l = l0 + t;
        const float4 t0 = *(const float4*)&dtr_g[l * 8];
        const float4 t1 = *(const float4*)&dtr_g[l * 8 + 4];
        float acc = bdv;
        acc += t0.x * wdt[0]; acc += t0.y * wdt[1]; acc += t0.z * wdt[2]; acc += t0.w * wdt[3];
        acc += t1.x * wdt[4]; acc += t1.y * wdt[5]; acc += t1.z * wdt[6]; acc += t1.w * wdt[7];
        const float dtv = softplus_f(acc);
        const float xcv = xc_g[l * DI + d];
        const float Bv = dbl_g[l * 32 + s];
        const float Cv = dbl_g[l * 32 + 16 + s];
        const float a = expf(dtv * A);
        h = a * h + dtv * xcv * Bv;
        prod[dl * 272 + s * 17 + t] = h * Cv;
    }
    __syncthreads();
    const int dl2 = tid & 15, tt = tid >> 4;
    const int l2 = l0 + tt, d2 = by * 16 + dl2;
    float sum = 0.f;
#pragma unroll
    for (int ss = 0; ss < 16; ++ss) sum += prod[dl2 * 272 + ss * 17 + tt];
    const float xcv2 = xc_g[l2 * DI + d2];
    const float zv = zbuf[l2 * DI + d2];
    y[l2 * DI + d2] = (sum + Dp[d2] * xcv2) * silu_f(zv);
}

// ---------------------------------------------------------------------------
// K5: out = rmsnorm(y @ W_out). grid 288; block 256 = 128 cols x 2 rowgroups(4).
template<bool LAST>
__global__ void k_out(const float* __restrict__ y, const float* __restrict__ Wo,
                      const float* __restrict__ rmsw, float* __restrict__ seq,
                      float* __restrict__ out) {
    __shared__ float Ys[8 * 256];
    __shared__ float Os[8 * 129];
    __shared__ float red[8 * 32];
    __shared__ float scale[8];
    const int l0 = blockIdx.x * 8;
    const int tid = threadIdx.x;
    for (int i = tid; i < 8 * 256; i += 256) Ys[i] = y[l0 * DI + i];
    __syncthreads();
    const int cc = tid & 127, rg = tid >> 7;
    float acc[4] = {0.f, 0.f, 0.f, 0.f};
    for (int k = 0; k < DI; ++k) {
        const float b = Wo[k * DM + cc];
#pragma unroll
        for (int rr = 0; rr < 4; ++rr) acc[rr] += Ys[(rg * 4 + rr) * 256 + k] * b;
    }
#pragma unroll
    for (int rr = 0; rr < 4; ++rr) Os[(rg * 4 + rr) * 129 + cc] = acc[rr];
    __syncthreads();
    {
        const int r = tid >> 5, part = tid & 31;
        float ss = 0.f;
#pragma unroll
        for (int i = 0; i < 4; ++i) {
            float v = Os[r * 129 + part * 4 + i];
            ss += v * v;
        }
        red[r * 32 + part] = ss;
    }
    __syncthreads();
    if (tid < 8) {
        float ss = 0.f;
#pragma unroll
        for (int p = 0; p < 32; ++p) ss += red[tid * 32 + p];
        scale[tid] = rsqrtf(ss * (1.f / DM) + EPSF);
    }
    __syncthreads();
    if (LAST) {
        for (int i = tid; i < 8 * DM; i += 256) {
            const int ccc = i >> 3, lr = i & 7;
            out[ccc * LSEQ + l0 + lr] = Os[lr * 129 + ccc] * scale[lr] * rmsw[ccc];
        }
    } else {
        const float rw = rmsw[cc];
#pragma unroll
        for (int rr = 0; rr < 4; ++rr) {
            const int r = rg * 4 + rr;
            seq[(l0 + r) * DM + cc] = Os[r * 129 + cc] * scale[r] * rw;
        }
    }
}

// ---------------------------------------------------------------------------
extern "C" void kernel_launch(void* const* d_in, const int* in_sizes, int n_in,
                              void* d_out, int out_size, void* d_ws, size_t ws_size,
                              hipStream_t stream) {
    const float* x    = (const float*)d_in[0];
    const float* W_in = (const float*)d_in[1];
    const float* cw   = (const float*)d_in[2];
    const float* cb   = (const float*)d_in[3];
    const float* Wx   = (const float*)d_in[4];
    const float* Wdt  = (const float*)d_in[5];
    const float* bdt  = (const float*)d_in[6];
    const float* Alog = (const float*)d_in[7];
    const float* Dp   = (const float*)d_in[8];
    const float* Wo   = (const float*)d_in[9];
    const float* rmsw = (const float*)d_in[10];
    float* out = (float*)d_out;

    float* ws   = (float*)d_ws;
    float* seq  = ws; ws += LSEQ * DM;       // 294912
    float* xbuf = ws; ws += LSEQ * DI;       // 589824
    float* zbuf = ws; ws += LSEQ * DI;       // 589824
    float* xcb  = ws; ws += LSEQ * DI;       // 589824
    float* dblb = ws; ws += LSEQ * 32;       // 73728
    float* dtrb = ws; ws += LSEQ * RK;       // 18432
    float* Pb   = ws; ws += NCH * DI * DS;   // 589824  (y aliases this after carry)
    float* Sb   = ws; ws += NCH * DI * DS;   // 589824  (becomes H in-place)
    float* yb   = Pb;

    for (int layer = 0; layer < 8; ++layer) {
        const float* Wi_l   = W_in + (size_t)layer * DM * 512;
        const float* cw_l   = cw   + (size_t)layer * DI * 4;
        const float* cb_l   = cb   + (size_t)layer * DI;
        const float* Wx_l   = Wx   + (size_t)layer * DI * 40;
        const float* Wdt_l  = Wdt  + (size_t)layer * RK * DI;
        const float* bdt_l  = bdt  + (size_t)layer * DI;
        const float* Alog_l = Alog + (size_t)layer * DI * DS;
        const float* Dp_l   = Dp   + (size_t)layer * DI;
        const float* Wo_l   = Wo   + (size_t)layer * DI * DM;
        const float* rmsw_l = rmsw + (size_t)layer * DM;

        if (layer == 0)
            k_gemm_in<true><<<dim3(NCH, 4), 256, 0, stream>>>(seq, x, Wi_l, xbuf, zbuf);
        else
            k_gemm_in<false><<<dim3(NCH, 4), 256, 0, stream>>>(seq, x, Wi_l, xbuf, zbuf);

        k_mid<<<NCH, 256, 0, stream>>>(xbuf, cw_l, cb_l, Wx_l, Wdt_l, bdt_l, Alog_l,
                                       xcb, dblb, dtrb, Pb, Sb);

        k_carry<<<16, 256, 0, stream>>>(Pb, Sb);

        k_scan2<<<dim3(NCH, DI / 16), 256, 0, stream>>>(xcb, dblb, dtrb, Wdt_l, bdt_l,
                                                        Alog_l, Sb, Dp_l, zbuf, yb);

        if (layer == 7)
            k_out<true><<<LSEQ / 8, 256, 0, stream>>>(yb, Wo_l, rmsw_l, seq, out);
        else
            k_out<false><<<LSEQ / 8, 256, 0, stream>>>(yb, Wo_l, rmsw_l, seq, out);
    }
}

// Round 3
// 1056.138 us; speedup vs baseline: 1.2156x; 1.0342x over previous
//
#include <hip/hip_runtime.h>
#include <math.h>

#define LSEQ 2304
#define DM 128
#define DI 256
#define DS 16
#define RK 8
#define NCH 144
#define CLEN 16
#define EPSF 1e-5f

__device__ __forceinline__ float silu_f(float s) { return s / (1.f + __expf(-s)); }
__device__ __forceinline__ float softplus_f(float x) { return (x > 20.f) ? x : log1pf(__expf(x)); }

// ---------------------------------------------------------------------------
// K1: [xbuf|zbuf] = seq @ W_in   (M=2304, K=128, N=512)
// grid (144, 4): 16 rows x 128 cols per block; 256 thr = 128 cols x 2 rowgroups.
template<bool FIRST>
__global__ __launch_bounds__(256, 4)
void k_gemm_in(const float* __restrict__ seq, const float* __restrict__ x0,
               const float* __restrict__ W, float* __restrict__ xbuf,
               float* __restrict__ zbuf) {
    __shared__ float As[16 * 129];
    const int l0 = blockIdx.x * 16;
    const int cb = blockIdx.y;  // 0..3
    const int tid = threadIdx.x;
    if (FIRST) {
        for (int i = tid; i < 16 * DM; i += 256) {
            int r = i & 15, c = i >> 4;
            As[r * 129 + c] = x0[c * LSEQ + l0 + r];
        }
    } else {
        for (int i = tid; i < 16 * DM; i += 256) {
            int c = i & 127, r = i >> 7;
            As[r * 129 + c] = seq[(l0 + r) * DM + c];
        }
    }
    __syncthreads();
    const int j = tid & 127;
    const int rg = tid >> 7;  // 0..1
    const int jg = cb * 128 + j;
    float acc[8];
#pragma unroll
    for (int rr = 0; rr < 8; ++rr) acc[rr] = 0.f;
    for (int k = 0; k < DM; ++k) {
        const float b = W[k * 512 + jg];
#pragma unroll
        for (int rr = 0; rr < 8; ++rr) acc[rr] += As[(rg * 8 + rr) * 129 + k] * b;
    }
    if (cb < 2) {
#pragma unroll
        for (int rr = 0; rr < 8; ++rr)
            xbuf[(l0 + rg * 8 + rr) * DI + jg] = acc[rr];
    } else {
#pragma unroll
        for (int rr = 0; rr < 8; ++rr)
            zbuf[(l0 + rg * 8 + rr) * DI + (jg - 256)] = acc[rr];
    }
}

// ---------------------------------------------------------------------------
// K2 (k_mid): conv4+silu -> xc ; xc @ W_xproj -> (dt_r, B, C) ; dt=softplus(...);
//             chunk-local scan -> P, S.   One block per 16-row chunk, 256 thr.
__global__ __launch_bounds__(256, 2)
void k_mid(const float* __restrict__ xbuf,
           const float* __restrict__ cw, const float* __restrict__ cbias,
           const float* __restrict__ Wx,
           const float* __restrict__ Wdt, const float* __restrict__ bdt,
           const float* __restrict__ Alog,
           float* __restrict__ xc_g, float* __restrict__ dbl_g,
           float* __restrict__ dtr_g,
           float* __restrict__ P, float* __restrict__ S) {
    __shared__ float xcs[16 * 256];   // [r][d]
    __shared__ float dbls[16 * 32];   // [r][j-8]
    __shared__ float dtrs[16 * 8];    // [r][q]
    const int c = blockIdx.x;
    const int l0 = c * CLEN;
    const int tid = threadIdx.x;

    // conv + silu (thread = channel d)
    const int d = tid;
    float xv[19];
#pragma unroll
    for (int t = 0; t < 19; ++t) {
        int l = l0 + t - 3;
        xv[t] = (l >= 0) ? xbuf[l * DI + d] : 0.f;
    }
    const float w0 = cw[d * 4 + 0], w1 = cw[d * 4 + 1];
    const float w2 = cw[d * 4 + 2], w3 = cw[d * 4 + 3];
    const float bias = cbias[d];
    float xcv[16];
#pragma unroll
    for (int r = 0; r < 16; ++r) {
        float sacc = bias + w0 * xv[r] + w1 * xv[r + 1] + w2 * xv[r + 2] + w3 * xv[r + 3];
        float v = silu_f(sacc);
        xcv[r] = v;
        xcs[r * 256 + d] = v;
        xc_g[(l0 + r) * DI + d] = v;
    }
    __syncthreads();

    // xproj: 640 outputs (16 r x 40 j), K=256. Wx read from global (L2-hot,
    // consecutive threads -> consecutive j -> coalesced). xcs reads broadcast.
    for (int idx = tid; idx < 16 * 40; idx += 256) {
        const int r = idx / 40, j = idx - r * 40;
        const float* xr = &xcs[r * 256];
        float acc = 0.f;
#pragma unroll 8
        for (int k = 0; k < 256; ++k) acc += xr[k] * Wx[k * 40 + j];
        if (j < RK) {
            dtrs[r * 8 + j] = acc;
            dtr_g[(l0 + r) * 8 + j] = acc;
        } else {
            dbls[r * 32 + (j - 8)] = acc;
            dbl_g[(l0 + r) * 32 + (j - 8)] = acc;
        }
    }
    __syncthreads();

    // dt = softplus(dt_r @ Wdt + bdt)  (thread = d, all 16 rows in regs)
    float wdt[8];
#pragma unroll
    for (int q = 0; q < 8; ++q) wdt[q] = Wdt[q * DI + d];
    const float bdv = bdt[d];
    float dtv[16];
#pragma unroll
    for (int r = 0; r < 16; ++r) {
        float acc = bdv;
#pragma unroll
        for (int q = 0; q < 8; ++q) acc += dtrs[r * 8 + q] * wdt[q];
        dtv[r] = softplus_f(acc);
    }

    // chunk-local scan: thread d holds 16 states
    float A[16], pr[16], hr[16];
    {
        const float4* Ap = (const float4*)&Alog[d * DS];
#pragma unroll
        for (int v = 0; v < 4; ++v) {
            float4 a4 = Ap[v];
            A[v * 4 + 0] = -__expf(a4.x);
            A[v * 4 + 1] = -__expf(a4.y);
            A[v * 4 + 2] = -__expf(a4.z);
            A[v * 4 + 3] = -__expf(a4.w);
        }
    }
#pragma unroll
    for (int s = 0; s < 16; ++s) { pr[s] = 1.f; hr[s] = 0.f; }
    for (int t = 0; t < CLEN; ++t) {
        const float dtt = dtv[t];
        const float commonv = dtt * xcv[t];
        const float* Brow = &dbls[t * 32];
#pragma unroll
        for (int s = 0; s < 16; ++s) {
            float a = __expf(dtt * A[s]);
            pr[s] *= a;
            hr[s] = a * hr[s] + commonv * Brow[s];
        }
    }
    const int base = c * (DI * DS) + d * DS;
    float4* Pp = (float4*)&P[base];
    float4* Sp = (float4*)&S[base];
#pragma unroll
    for (int v = 0; v < 4; ++v) {
        Pp[v] = make_float4(pr[v * 4], pr[v * 4 + 1], pr[v * 4 + 2], pr[v * 4 + 3]);
        Sp[v] = make_float4(hr[v * 4], hr[v * 4 + 1], hr[v * 4 + 2], hr[v * 4 + 3]);
    }
}

// ---------------------------------------------------------------------------
// K3: chunk carries, in place: S[c] <- carry INTO chunk c. grid 16 x 256.
__global__ __launch_bounds__(256, 4)
void k_carry(const float* __restrict__ P, float* __restrict__ S) {
    const int i = blockIdx.x * 256 + threadIdx.x;
    float h = 0.f;
#pragma unroll 4
    for (int c = 0; c < NCH; ++c) {
        const int idx = c * (DI * DS) + i;
        const float p = P[idx];
        const float s = S[idx];
        S[idx] = h;
        h = p * h + s;
    }
}

// ---------------------------------------------------------------------------
// K4: re-scan with carry + C-reduction via LDS transpose + gate -> y.
// grid (144, 16); block 256 = 16 d x 16 s.
__global__ __launch_bounds__(256, 4)
void k_scan2(const float* __restrict__ xc_g, const float* __restrict__ dbl_g,
             const float* __restrict__ dtr_g,
             const float* __restrict__ Wdt, const float* __restrict__ bdt,
             const float* __restrict__ Alog, const float* __restrict__ H,
             const float* __restrict__ Dp, const float* __restrict__ zbuf,
             float* __restrict__ y) {
    __shared__ float prod[16 * 16 * 17];  // [dl][s][t pad 17]
    const int c = blockIdx.x, by = blockIdx.y;
    const int tid = threadIdx.x;
    const int dl = tid >> 4, s = tid & 15;
    const int d = by * 16 + dl;
    const float A = -__expf(Alog[d * DS + s]);
    float wdt[8];
#pragma unroll
    for (int q = 0; q < 8; ++q) wdt[q] = Wdt[q * DI + d];
    const float bdv = bdt[d];
    float h = H[c * (DI * DS) + by * 256 + tid];
    const int l0 = c * CLEN;
    for (int t = 0; t < CLEN; ++t) {
        const int l = l0 + t;
        const float4 t0 = *(const float4*)&dtr_g[l * 8];
        const float4 t1 = *(const float4*)&dtr_g[l * 8 + 4];
        float acc = bdv;
        acc += t0.x * wdt[0]; acc += t0.y * wdt[1]; acc += t0.z * wdt[2]; acc += t0.w * wdt[3];
        acc += t1.x * wdt[4]; acc += t1.y * wdt[5]; acc += t1.z * wdt[6]; acc += t1.w * wdt[7];
        const float dtv = softplus_f(acc);
        const float xcv = xc_g[l * DI + d];
        const float Bv = dbl_g[l * 32 + s];
        const float Cv = dbl_g[l * 32 + 16 + s];
        const float a = __expf(dtv * A);
        h = a * h + dtv * xcv * Bv;
        prod[dl * 272 + s * 17 + t] = h * Cv;
    }
    __syncthreads();
    const int dl2 = tid & 15, tt = tid >> 4;
    const int l2 = l0 + tt, d2 = by * 16 + dl2;
    float sum = 0.f;
#pragma unroll
    for (int ss = 0; ss < 16; ++ss) sum += prod[dl2 * 272 + ss * 17 + tt];
    const float xcv2 = xc_g[l2 * DI + d2];
    const float zv = zbuf[l2 * DI + d2];
    y[l2 * DI + d2] = (sum + Dp[d2] * xcv2) * silu_f(zv);
}

// ---------------------------------------------------------------------------
// K5: out = rmsnorm(y @ W_out). grid 288; block 256 = 128 cols x 2 rowgroups(4).
template<bool LAST>
__global__ __launch_bounds__(256, 4)
void k_out(const float* __restrict__ y, const float* __restrict__ Wo,
           const float* __restrict__ rmsw, float* __restrict__ seq,
           float* __restrict__ out) {
    __shared__ float Ys[8 * 256];
    __shared__ float Os[8 * 129];
    __shared__ float red[8 * 32];
    __shared__ float scale[8];
    const int l0 = blockIdx.x * 8;
    const int tid = threadIdx.x;
    for (int i = tid; i < 8 * 256; i += 256) Ys[i] = y[l0 * DI + i];
    __syncthreads();
    const int cc = tid & 127, rg = tid >> 7;
    float acc[4] = {0.f, 0.f, 0.f, 0.f};
    for (int k = 0; k < DI; ++k) {
        const float b = Wo[k * DM + cc];
#pragma unroll
        for (int rr = 0; rr < 4; ++rr) acc[rr] += Ys[(rg * 4 + rr) * 256 + k] * b;
    }
#pragma unroll
    for (int rr = 0; rr < 4; ++rr) Os[(rg * 4 + rr) * 129 + cc] = acc[rr];
    __syncthreads();
    {
        const int r = tid >> 5, part = tid & 31;
        float ss = 0.f;
#pragma unroll
        for (int i = 0; i < 4; ++i) {
            float v = Os[r * 129 + part * 4 + i];
            ss += v * v;
        }
        red[r * 32 + part] = ss;
    }
    __syncthreads();
    if (tid < 8) {
        float ss = 0.f;
#pragma unroll
        for (int p = 0; p < 32; ++p) ss += red[tid * 32 + p];
        scale[tid] = rsqrtf(ss * (1.f / DM) + EPSF);
    }
    __syncthreads();
    if (LAST) {
        for (int i = tid; i < 8 * DM; i += 256) {
            const int ccc = i >> 3, lr = i & 7;
            out[ccc * LSEQ + l0 + lr] = Os[lr * 129 + ccc] * scale[lr] * rmsw[ccc];
        }
    } else {
        const float rw = rmsw[cc];
#pragma unroll
        for (int rr = 0; rr < 4; ++rr) {
            const int r = rg * 4 + rr;
            seq[(l0 + r) * DM + cc] = Os[r * 129 + cc] * scale[r] * rw;
        }
    }
}

// ---------------------------------------------------------------------------
extern "C" void kernel_launch(void* const* d_in, const int* in_sizes, int n_in,
                              void* d_out, int out_size, void* d_ws, size_t ws_size,
                              hipStream_t stream) {
    const float* x    = (const float*)d_in[0];
    const float* W_in = (const float*)d_in[1];
    const float* cw   = (const float*)d_in[2];
    const float* cb   = (const float*)d_in[3];
    const float* Wx   = (const float*)d_in[4];
    const float* Wdt  = (const float*)d_in[5];
    const float* bdt  = (const float*)d_in[6];
    const float* Alog = (const float*)d_in[7];
    const float* Dp   = (const float*)d_in[8];
    const float* Wo   = (const float*)d_in[9];
    const float* rmsw = (const float*)d_in[10];
    float* out = (float*)d_out;

    float* ws   = (float*)d_ws;
    float* seq  = ws; ws += LSEQ * DM;
    float* xbuf = ws; ws += LSEQ * DI;
    float* zbuf = ws; ws += LSEQ * DI;
    float* xcb  = ws; ws += LSEQ * DI;
    float* dblb = ws; ws += LSEQ * 32;
    float* dtrb = ws; ws += LSEQ * RK;
    float* Pb   = ws; ws += NCH * DI * DS;
    float* Sb   = ws; ws += NCH * DI * DS;
    float* yb   = Pb;  // alias: P dead after k_carry

    for (int layer = 0; layer < 8; ++layer) {
        const float* Wi_l   = W_in + (size_t)layer * DM * 512;
        const float* cw_l   = cw   + (size_t)layer * DI * 4;
        const float* cb_l   = cb   + (size_t)layer * DI;
        const float* Wx_l   = Wx   + (size_t)layer * DI * 40;
        const float* Wdt_l  = Wdt  + (size_t)layer * RK * DI;
        const float* bdt_l  = bdt  + (size_t)layer * DI;
        const float* Alog_l = Alog + (size_t)layer * DI * DS;
        const float* Dp_l   = Dp   + (size_t)layer * DI;
        const float* Wo_l   = Wo   + (size_t)layer * DI * DM;
        const float* rmsw_l = rmsw + (size_t)layer * DM;

        if (layer == 0)
            k_gemm_in<true><<<dim3(NCH, 4), 256, 0, stream>>>(seq, x, Wi_l, xbuf, zbuf);
        else
            k_gemm_in<false><<<dim3(NCH, 4), 256, 0, stream>>>(seq, x, Wi_l, xbuf, zbuf);

        k_mid<<<NCH, 256, 0, stream>>>(xbuf, cw_l, cb_l, Wx_l, Wdt_l, bdt_l, Alog_l,
                                       xcb, dblb, dtrb, Pb, Sb);

        k_carry<<<16, 256, 0, stream>>>(Pb, Sb);

        k_scan2<<<dim3(NCH, DI / 16), 256, 0, stream>>>(xcb, dblb, dtrb, Wdt_l, bdt_l,
                                                        Alog_l, Sb, Dp_l, zbuf, yb);

        if (layer == 7)
            k_out<true><<<LSEQ / 8, 256, 0, stream>>>(yb, Wo_l, rmsw_l, seq, out);
        else
            k_out<false><<<LSEQ / 8, 256, 0, stream>>>(yb, Wo_l, rmsw_l, seq, out);
    }
}

// Round 4
// 777.253 us; speedup vs baseline: 1.6518x; 1.3588x over previous
//
#include <hip/hip_runtime.h>
#include <math.h>

#define LSEQ 2304
#define DM 128
#define DI 256
#define DS 16
#define RK 8
#define NCH 144
#define CLEN 16
#define EPSF 1e-5f

__device__ __forceinline__ float silu_f(float s) { return s / (1.f + __expf(-s)); }
__device__ __forceinline__ float softplus_f(float x) { return (x > 20.f) ? x : log1pf(__expf(x)); }

// ---------------------------------------------------------------------------
// K1: [xbuf | silu(z)] = seq @ W_in   (M=2304, K=128, N=512)
// grid (288, 4): 8 rows x 128 cols per block; 256 thr = 128 cols x 2 rowgroups.
template<bool FIRST>
__global__ __launch_bounds__(256, 4)
void k_gemm_in(const float* __restrict__ seq, const float* __restrict__ x0,
               const float* __restrict__ W, float* __restrict__ xbuf,
               float* __restrict__ sz) {
    __shared__ float As[8 * 129];
    const int l0 = blockIdx.x * 8;
    const int cb = blockIdx.y;  // 0..3
    const int tid = threadIdx.x;
    if (FIRST) {
        for (int i = tid; i < 8 * DM; i += 256) {
            int r = i & 7, c = i >> 3;
            As[r * 129 + c] = x0[c * LSEQ + l0 + r];
        }
    } else {
        for (int i = tid; i < 8 * DM; i += 256) {
            int c = i & 127, r = i >> 7;
            As[r * 129 + c] = seq[(l0 + r) * DM + c];
        }
    }
    __syncthreads();
    const int j = tid & 127;
    const int rg = tid >> 7;  // 0..1 -> rows rg*4 .. rg*4+3
    const int jg = cb * 128 + j;
    float acc[4] = {0.f, 0.f, 0.f, 0.f};
    for (int k = 0; k < DM; ++k) {
        const float b = W[k * 512 + jg];
#pragma unroll
        for (int rr = 0; rr < 4; ++rr) acc[rr] += As[(rg * 4 + rr) * 129 + k] * b;
    }
    if (cb < 2) {
#pragma unroll
        for (int rr = 0; rr < 4; ++rr)
            xbuf[(l0 + rg * 4 + rr) * DI + jg] = acc[rr];
    } else {
#pragma unroll
        for (int rr = 0; rr < 4; ++rr)
            sz[(l0 + rg * 4 + rr) * DI + (jg - 256)] = silu_f(acc[rr]);
    }
}

// ---------------------------------------------------------------------------
// K2: causal conv4 + silu -> xc. grid 576; block 256 = 4 rows x 64 d-quads.
__global__ __launch_bounds__(256, 4)
void k_conv(const float* __restrict__ xbuf, const float* __restrict__ cw,
            const float* __restrict__ cbias, float* __restrict__ xc) {
    const int tid = threadIdx.x;
    const int l = blockIdx.x * 4 + (tid >> 6);
    const int d4 = (tid & 63) * 4;
    const float4 wA = *(const float4*)&cw[d4 * 4];       // weights for d4+0
    const float4 wB = *(const float4*)&cw[d4 * 4 + 4];   // d4+1
    const float4 wC = *(const float4*)&cw[d4 * 4 + 8];   // d4+2
    const float4 wD = *(const float4*)&cw[d4 * 4 + 12];  // d4+3
    const float4 bias = *(const float4*)&cbias[d4];
    const float4 zero = make_float4(0.f, 0.f, 0.f, 0.f);
    float4 t0 = (l >= 3) ? *(const float4*)&xbuf[(l - 3) * DI + d4] : zero;
    float4 t1 = (l >= 2) ? *(const float4*)&xbuf[(l - 2) * DI + d4] : zero;
    float4 t2 = (l >= 1) ? *(const float4*)&xbuf[(l - 1) * DI + d4] : zero;
    float4 t3 = *(const float4*)&xbuf[l * DI + d4];
    float4 o;
    o.x = bias.x + wA.x * t0.x + wA.y * t1.x + wA.z * t2.x + wA.w * t3.x;
    o.y = bias.y + wB.x * t0.y + wB.y * t1.y + wB.z * t2.y + wB.w * t3.y;
    o.z = bias.z + wC.x * t0.z + wC.y * t1.z + wC.z * t2.z + wC.w * t3.z;
    o.w = bias.w + wD.x * t0.w + wD.y * t1.w + wD.z * t2.w + wD.w * t3.w;
    o.x = silu_f(o.x); o.y = silu_f(o.y); o.z = silu_f(o.z); o.w = silu_f(o.w);
    *(float4*)&xc[l * DI + d4] = o;
}

// ---------------------------------------------------------------------------
// K3: xc @ W_xproj -> (dtr, B, C); dt = softplus(dtr @ Wdt + bdt) -> dt_g.
// grid 288; block 320 (8 rows x 40 cols, 1 output/thread in phase A).
__global__ __launch_bounds__(320, 2)
void k_xproj(const float* __restrict__ xc, const float* __restrict__ Wx,
             const float* __restrict__ Wdt, const float* __restrict__ bdt,
             float* __restrict__ dbl_g, float* __restrict__ dt_g) {
    __shared__ float xcs[8 * 256];
    __shared__ float dtrs[8 * 8];
    const int l0 = blockIdx.x * 8;
    const int tid = threadIdx.x;
    for (int i = tid; i < 8 * 256; i += 320) xcs[i] = xc[l0 * DI + i];
    __syncthreads();
    {
        const int r = tid / 40, j = tid - r * 40;
        const float* xr = &xcs[r * 256];
        float acc = 0.f;
#pragma unroll 8
        for (int k = 0; k < 256; ++k) acc += xr[k] * Wx[k * 40 + j];
        if (j < RK) dtrs[r * 8 + j] = acc;
        else dbl_g[(l0 + r) * 32 + (j - 8)] = acc;
    }
    __syncthreads();
    if (tid < 256) {
        const int d = tid;
        float wdt[8];
#pragma unroll
        for (int q = 0; q < 8; ++q) wdt[q] = Wdt[q * DI + d];
        const float bdv = bdt[d];
#pragma unroll
        for (int r = 0; r < 8; ++r) {
            float acc = bdv;
#pragma unroll
            for (int q = 0; q < 8; ++q) acc += dtrs[r * 8 + q] * wdt[q];
            dt_g[(l0 + r) * DI + d] = softplus_f(acc);
        }
    }
}

// ---------------------------------------------------------------------------
// K4: chunk-local scan -> (P, S). grid (144, 4); block 256 (thread = d, 4 s).
__global__ __launch_bounds__(256, 4)
void k_scan1(const float* __restrict__ dt, const float* __restrict__ xc,
             const float* __restrict__ dbl_g, const float* __restrict__ Alog,
             float* __restrict__ P, float* __restrict__ S) {
    __shared__ float Bs[CLEN * 4];
    const int c = blockIdx.x, q = blockIdx.y;
    const int d = threadIdx.x;
    const int l0 = c * CLEN;
    if (threadIdx.x < CLEN * 4) {
        const int t = threadIdx.x >> 2, ss = threadIdx.x & 3;
        Bs[threadIdx.x] = dbl_g[(l0 + t) * 32 + q * 4 + ss];
    }
    const float4 a4 = *(const float4*)&Alog[d * DS + q * 4];
    const float A0 = -__expf(a4.x), A1 = -__expf(a4.y);
    const float A2 = -__expf(a4.z), A3 = -__expf(a4.w);
    __syncthreads();
    float p0 = 1.f, p1 = 1.f, p2 = 1.f, p3 = 1.f;
    float h0 = 0.f, h1 = 0.f, h2 = 0.f, h3 = 0.f;
    for (int t = 0; t < CLEN; ++t) {
        const int l = l0 + t;
        const float dtv = dt[l * DI + d];
        const float uv = dtv * xc[l * DI + d];
        const float b0 = Bs[t * 4 + 0], b1 = Bs[t * 4 + 1];
        const float b2 = Bs[t * 4 + 2], b3 = Bs[t * 4 + 3];
        const float e0 = __expf(dtv * A0); p0 *= e0; h0 = e0 * h0 + uv * b0;
        const float e1 = __expf(dtv * A1); p1 *= e1; h1 = e1 * h1 + uv * b1;
        const float e2 = __expf(dtv * A2); p2 *= e2; h2 = e2 * h2 + uv * b2;
        const float e3 = __expf(dtv * A3); p3 *= e3; h3 = e3 * h3 + uv * b3;
    }
    const int base = c * (DI * DS) + d * DS + q * 4;
    *(float4*)&P[base] = make_float4(p0, p1, p2, p3);
    *(float4*)&S[base] = make_float4(h0, h1, h2, h3);
}

// ---------------------------------------------------------------------------
// K5: chunk carries in place: S[c] <- carry INTO chunk c. grid 64 x 64.
__global__ __launch_bounds__(64, 8)
void k_carry(const float* __restrict__ P, float* __restrict__ S) {
    const int i = blockIdx.x * 64 + threadIdx.x;
    float h = 0.f;
#pragma unroll 4
    for (int c = 0; c < NCH; ++c) {
        const int idx = c * (DI * DS) + i;
        const float p = P[idx];
        const float s = S[idx];
        S[idx] = h;
        h = p * h + s;
    }
}

// ---------------------------------------------------------------------------
// K6: re-scan with carry + C-reduce + gate -> y. grid (144, 16); block 256.
__global__ __launch_bounds__(256, 4)
void k_scan2(const float* __restrict__ dt, const float* __restrict__ xc,
             const float* __restrict__ dbl_g, const float* __restrict__ Alog,
             const float* __restrict__ H, const float* __restrict__ Dp,
             const float* __restrict__ sz, float* __restrict__ y) {
    __shared__ float dbls[CLEN * 32];
    __shared__ float prod[16 * 16 * 17];
    const int c = blockIdx.x, by = blockIdx.y;
    const int tid = threadIdx.x;
    const int dl = tid >> 4, s = tid & 15;
    const int d = by * 16 + dl;
    const int l0 = c * CLEN;
    for (int i = tid; i < CLEN * 32; i += 256) dbls[i] = dbl_g[l0 * 32 + i];
    const float A = -__expf(Alog[by * 256 + tid]);  // Alog[d*16+s]
    float h = H[c * (DI * DS) + by * 256 + tid];
    __syncthreads();
    for (int t = 0; t < CLEN; ++t) {
        const int l = l0 + t;
        const float dtv = dt[l * DI + d];
        const float uv = dtv * xc[l * DI + d];
        const float a = __expf(dtv * A);
        h = a * h + uv * dbls[t * 32 + s];
        prod[dl * 272 + s * 17 + t] = h * dbls[t * 32 + 16 + s];
    }
    __syncthreads();
    const int dl2 = tid & 15, tt = tid >> 4;
    const int l2 = l0 + tt, d2 = by * 16 + dl2;
    float sum = 0.f;
#pragma unroll
    for (int ss = 0; ss < 16; ++ss) sum += prod[dl2 * 272 + ss * 17 + tt];
    y[l2 * DI + d2] = (sum + Dp[d2] * xc[l2 * DI + d2]) * sz[l2 * DI + d2];
}

// ---------------------------------------------------------------------------
// K7: out = rmsnorm(y @ W_out). grid 288; block 256 = 128 cols x 2 rowgroups(4).
template<bool LAST>
__global__ __launch_bounds__(256, 4)
void k_out(const float* __restrict__ y, const float* __restrict__ Wo,
           const float* __restrict__ rmsw, float* __restrict__ seq,
           float* __restrict__ out) {
    __shared__ float Ys[8 * 256];
    __shared__ float Os[8 * 129];
    __shared__ float red[8 * 32];
    __shared__ float scale[8];
    const int l0 = blockIdx.x * 8;
    const int tid = threadIdx.x;
    for (int i = tid; i < 8 * 256; i += 256) Ys[i] = y[l0 * DI + i];
    __syncthreads();
    const int cc = tid & 127, rg = tid >> 7;
    float acc[4] = {0.f, 0.f, 0.f, 0.f};
    for (int k = 0; k < DI; ++k) {
        const float b = Wo[k * DM + cc];
#pragma unroll
        for (int rr = 0; rr < 4; ++rr) acc[rr] += Ys[(rg * 4 + rr) * 256 + k] * b;
    }
#pragma unroll
    for (int rr = 0; rr < 4; ++rr) Os[(rg * 4 + rr) * 129 + cc] = acc[rr];
    __syncthreads();
    {
        const int r = tid >> 5, part = tid & 31;
        float ss = 0.f;
#pragma unroll
        for (int i = 0; i < 4; ++i) {
            float v = Os[r * 129 + part * 4 + i];
            ss += v * v;
        }
        red[r * 32 + part] = ss;
    }
    __syncthreads();
    if (tid < 8) {
        float ss = 0.f;
#pragma unroll
        for (int p = 0; p < 32; ++p) ss += red[tid * 32 + p];
        scale[tid] = rsqrtf(ss * (1.f / DM) + EPSF);
    }
    __syncthreads();
    if (LAST) {
        for (int i = tid; i < 8 * DM; i += 256) {
            const int ccc = i >> 3, lr = i & 7;
            out[ccc * LSEQ + l0 + lr] = Os[lr * 129 + ccc] * scale[lr] * rmsw[ccc];
        }
    } else {
        const float rw = rmsw[cc];
#pragma unroll
        for (int rr = 0; rr < 4; ++rr) {
            const int r = rg * 4 + rr;
            seq[(l0 + r) * DM + cc] = Os[r * 129 + cc] * scale[r] * rw;
        }
    }
}

// ---------------------------------------------------------------------------
extern "C" void kernel_launch(void* const* d_in, const int* in_sizes, int n_in,
                              void* d_out, int out_size, void* d_ws, size_t ws_size,
                              hipStream_t stream) {
    const float* x    = (const float*)d_in[0];
    const float* W_in = (const float*)d_in[1];
    const float* cw   = (const float*)d_in[2];
    const float* cb   = (const float*)d_in[3];
    const float* Wx   = (const float*)d_in[4];
    const float* Wdt  = (const float*)d_in[5];
    const float* bdt  = (const float*)d_in[6];
    const float* Alog = (const float*)d_in[7];
    const float* Dp   = (const float*)d_in[8];
    const float* Wo   = (const float*)d_in[9];
    const float* rmsw = (const float*)d_in[10];
    float* out = (float*)d_out;

    float* ws   = (float*)d_ws;
    float* seq  = ws; ws += LSEQ * DM;       // 294912
    float* xbuf = ws; ws += LSEQ * DI;       // 589824 ; dt aliases after conv
    float* szb  = ws; ws += LSEQ * DI;       // 589824 ; y aliases (elementwise)
    float* xcb  = ws; ws += LSEQ * DI;       // 589824
    float* dblb = ws; ws += LSEQ * 32;       // 73728
    float* Pb   = ws; ws += NCH * DI * DS;   // 589824
    float* Sb   = ws; ws += NCH * DI * DS;   // 589824  (becomes H in place)
    float* dtb  = xbuf;  // xbuf dead after k_conv
    float* yb   = szb;   // scan2 reads sz[i] then writes y[i] (same thread)

    for (int layer = 0; layer < 8; ++layer) {
        const float* Wi_l   = W_in + (size_t)layer * DM * 512;
        const float* cw_l   = cw   + (size_t)layer * DI * 4;
        const float* cb_l   = cb   + (size_t)layer * DI;
        const float* Wx_l   = Wx   + (size_t)layer * DI * 40;
        const float* Wdt_l  = Wdt  + (size_t)layer * RK * DI;
        const float* bdt_l  = bdt  + (size_t)layer * DI;
        const float* Alog_l = Alog + (size_t)layer * DI * DS;
        const float* Dp_l   = Dp   + (size_t)layer * DI;
        const float* Wo_l   = Wo   + (size_t)layer * DI * DM;
        const float* rmsw_l = rmsw + (size_t)layer * DM;

        if (layer == 0)
            k_gemm_in<true><<<dim3(288, 4), 256, 0, stream>>>(seq, x, Wi_l, xbuf, szb);
        else
            k_gemm_in<false><<<dim3(288, 4), 256, 0, stream>>>(seq, x, Wi_l, xbuf, szb);

        k_conv<<<576, 256, 0, stream>>>(xbuf, cw_l, cb_l, xcb);

        k_xproj<<<288, 320, 0, stream>>>(xcb, Wx_l, Wdt_l, bdt_l, dblb, dtb);

        k_scan1<<<dim3(NCH, 4), 256, 0, stream>>>(dtb, xcb, dblb, Alog_l, Pb, Sb);

        k_carry<<<64, 64, 0, stream>>>(Pb, Sb);

        k_scan2<<<dim3(NCH, 16), 256, 0, stream>>>(dtb, xcb, dblb, Alog_l, Sb,
                                                   Dp_l, szb, yb);

        if (layer == 7)
            k_out<true><<<LSEQ / 8, 256, 0, stream>>>(yb, Wo_l, rmsw_l, seq, out);
        else
            k_out<false><<<LSEQ / 8, 256, 0, stream>>>(yb, Wo_l, rmsw_l, seq, out);
    }
}